// Round 8
// baseline (402.637 us; speedup 1.0000x reference)
//
#include <hip/hip_runtime.h>
#include <hip/hip_fp16.h>

// ---------------------------------------------------------------------------
// VariationalGCNEncoder on MI355X
//   radix partition by dst -> fused bucket CSR build (self-loop record
//   embedded, pair-padded to 16-slot multiples)
//   wprep: W1^T, [Wmu|Wls]^T -> fp16 [col][K]; bias2 = bmu||bls
//   h  = x @ W1                (MFMA fp16, slice-major out)
//   h1 = relu(A @ h + b1)      (gather_slice: channel-sliced, XCD-L2-resident)
//   p  = h1 @ [Wmu|Wls]        (MFMA fp16, slice-major in/out)
//   mu|logstd = A @ p + bias2  (gather_slice, f32 split out)
// Slice-major: hs[s][node][16ch] fp16 -> 3.2MB/slice fits one XCD's 4MB L2;
// blockIdx%8 = slice rides the round-robin XCD dispatch.
// ---------------------------------------------------------------------------

#define NBUCKET 1024
#define NPB 512  // partition blocks; chunk = ceil(E/NPB)

typedef _Float16 half8_t __attribute__((ext_vector_type(8)));
typedef float f32x4_t __attribute__((ext_vector_type(4)));

// ---- partition pass 1: per-block bucket histogram --------------------------
__global__ __launch_bounds__(256) void hist_pass(const int* __restrict__ dst, int E,
                                                 int chunk, int shift,
                                                 int* __restrict__ blk_hist) {
    __shared__ int hist[NBUCKET];
    for (int i = threadIdx.x; i < NBUCKET; i += 256) hist[i] = 0;
    __syncthreads();
    int b = blockIdx.x;
    int beg = b * chunk;
    int end = beg + chunk; if (end > E) end = E;
    for (int i = beg + threadIdx.x; i < end; i += 256)
        atomicAdd(&hist[dst[i] >> shift], 1);
    __syncthreads();
    for (int i = threadIdx.x; i < NBUCKET; i += 256)
        blk_hist[(size_t)b * NBUCKET + i] = hist[i];
}

// ---- partition pass 2: per-bucket column scan (one block per bucket) -------
__global__ __launch_bounds__(256) void col_scan(const int* __restrict__ blk_hist,
                                                int* __restrict__ blk_base,
                                                int* __restrict__ bucket_total) {
    __shared__ int sh[256];
    int q = blockIdx.x, t = threadIdx.x;
    int v0 = blk_hist[(size_t)(2 * t) * NBUCKET + q];
    int v1 = blk_hist[(size_t)(2 * t + 1) * NBUCKET + q];
    int s = v0 + v1;
    sh[t] = s;
    __syncthreads();
    for (int off = 1; off < 256; off <<= 1) {
        int x = (t >= off) ? sh[t - off] : 0;
        __syncthreads();
        sh[t] += x;
        __syncthreads();
    }
    int pre = sh[t] - s;
    blk_base[(size_t)(2 * t) * NBUCKET + q] = pre;
    blk_base[(size_t)(2 * t + 1) * NBUCKET + q] = pre + v0;
    if (t == 255) bucket_total[q] = sh[255];
}

// ---- exclusive scan of 1024 values (single block), used twice --------------
__global__ __launch_bounds__(256) void scan_bucket(const int* __restrict__ total,
                                                   int* __restrict__ base) {
    __shared__ int sh[256];
    int t = threadIdx.x;
    int idx0 = t * 4;
    int v[4];
#pragma unroll
    for (int k = 0; k < 4; ++k) v[k] = total[idx0 + k];
    int s = v[0] + v[1] + v[2] + v[3];
    sh[t] = s;
    __syncthreads();
    for (int off = 1; off < 256; off <<= 1) {
        int x = (t >= off) ? sh[t - off] : 0;
        __syncthreads();
        sh[t] += x;
        __syncthreads();
    }
    int run = sh[t] - s;
#pragma unroll
    for (int k = 0; k < 4; ++k) {
        base[idx0 + k] = run;
        run += v[k];
    }
}

// ---- partition pass 3: scatter (dst,src) pairs into bucket-ordered part[] --
__global__ __launch_bounds__(256) void scatter_pass(const int* __restrict__ src,
                                                    const int* __restrict__ dst, int E,
                                                    int chunk, int shift,
                                                    const int* __restrict__ bucket_base,
                                                    const int* __restrict__ blk_base,
                                                    long long* __restrict__ part) {
    __shared__ int cur[NBUCKET];
    int b = blockIdx.x;
    for (int i = threadIdx.x; i < NBUCKET; i += 256)
        cur[i] = bucket_base[i] + blk_base[(size_t)b * NBUCKET + i];
    __syncthreads();
    int beg = b * chunk;
    int end = beg + chunk; if (end > E) end = E;
    for (int i = beg + threadIdx.x; i < end; i += 256) {
        int d = dst[i], s = src[i];
        int q = d >> shift;
        int p = atomicAdd(&cur[q], 1);
        part[p] = ((long long)(unsigned)d << 32) | (unsigned)s;
    }
}

// ---- bucket_count: LDS count -> degi, dinv, padded bucket total -------------
// Slots per node = deg + 1 (self-loop record); pair-padded to 16 multiples.
__global__ __launch_bounds__(256) void bucket_count(const long long* __restrict__ part,
                                                    const int* __restrict__ bucket_base,
                                                    const int* __restrict__ bucket_total,
                                                    int N, int shift,
                                                    int* __restrict__ degi,
                                                    float* __restrict__ dinv,
                                                    int* __restrict__ padded_total) {
    __shared__ int cnt[128];
    __shared__ int sh[128];
    int b = blockIdx.x, t = threadIdx.x;
    if (t < 128) cnt[t] = 0;
    __syncthreads();
    int node0 = b << shift;
    int beg = bucket_base[b];
    int end = beg + bucket_total[b];
    for (int i = beg + t; i < end; i += 256) {
        int d = (int)((unsigned long long)part[i] >> 32);
        atomicAdd(&cnt[d - node0], 1);
    }
    __syncthreads();
    if (t < 128) {
        int node = node0 + t;
        int c = (node < N) ? cnt[t] : 0;
        if (node < N) {
            degi[node] = c;
            dinv[node] = rsqrtf((float)(c + 1));
        }
        sh[t] = c;
    }
    __syncthreads();
    int padded = 0;
    if (t < 128) {
        int node = node0 + t;
        if (node < N) {
            int mine = (sh[t] + 16) >> 4;          // ceil((deg+1)/16)
            int pi = t ^ 1;
            int pnode = node0 + pi;
            int theirs = (pnode < N) ? ((sh[pi] + 16) >> 4) : 0;
            int L = mine > theirs ? mine : theirs;
            padded = L << 4;
        }
    }
    __syncthreads();
    if (t < 128) sh[t] = padded;
    __syncthreads();
    for (int off = 64; off >= 1; off >>= 1) {
        if (t < off) sh[t] += sh[t + off];
        __syncthreads();
    }
    if (t == 0) padded_total[b] = sh[0];
}

// ---- bucket_fill: row_ptr + self rec + weighted scatter into padded csr2 ----
__global__ __launch_bounds__(256) void bucket_fill(const long long* __restrict__ part,
                                                   const int* __restrict__ bucket_base,
                                                   const int* __restrict__ bucket_total,
                                                   const int* __restrict__ padded_base,
                                                   const int* __restrict__ degi,
                                                   const float* __restrict__ dinv,
                                                   int N, int shift,
                                                   int* __restrict__ row_ptr,
                                                   long long* __restrict__ csr2) {
    __shared__ int sh[128];
    __shared__ int pexcl[128];
    __shared__ int padarr[128];
    __shared__ int cur[128];
    __shared__ float dvl[128];
    int b = blockIdx.x, t = threadIdx.x;
    int node0 = b << shift;
    int pbase = padded_base[b];

    if (t < 128) {
        int node = node0 + t;
        int deg = (node < N) ? degi[node] : 0;
        dvl[t] = (node < N) ? dinv[node] : 0.0f;
        sh[t] = deg;
    }
    __syncthreads();
    int padded = 0;
    if (t < 128) {
        int node = node0 + t;
        if (node < N) {
            int mine = (sh[t] + 16) >> 4;
            int pi = t ^ 1;
            int pnode = node0 + pi;
            int theirs = (pnode < N) ? ((sh[pi] + 16) >> 4) : 0;
            int L = mine > theirs ? mine : theirs;
            padded = L << 4;
        }
        padarr[t] = padded;
    }
    __syncthreads();
    if (t < 128) sh[t] = padded;
    __syncthreads();
    for (int off = 1; off < 128; off <<= 1) {
        int x = 0;
        if (t < 128 && t >= off) x = sh[t - off];
        __syncthreads();
        if (t < 128) sh[t] += x;
        __syncthreads();
    }
    if (t < 128) {
        int excl = sh[t] - padarr[t];
        pexcl[t] = excl;
        int node = node0 + t;
        if (node < N) {
            row_ptr[node] = pbase + excl;
            // self-loop record first: (src=node, w=dinv^2)
            float ws = dvl[t] * dvl[t];
            csr2[pbase + excl] = (long long)(unsigned)node |
                                 ((long long)(unsigned)__float_as_uint(ws) << 32);
            cur[t] = pbase + excl + 1;
        } else {
            cur[t] = pbase + excl;
        }
    }
    __syncthreads();
    if (t == 0) {
        int boundary = node0 + 128;
        if (boundary > N) boundary = N;
        row_ptr[boundary] = pbase + sh[127];  // benign overlap with next bucket
    }
    int ebeg = bucket_base[b];
    int eend = ebeg + bucket_total[b];
    for (int i = ebeg + t; i < eend; i += 256) {
        long long pr = part[i];
        int d = (int)((unsigned long long)pr >> 32);
        int s = (int)(unsigned)(pr & 0xffffffffLL);
        int dl = d - node0;
        int p = atomicAdd(&cur[dl], 1);
        float w = dinv[s] * dvl[dl];
        csr2[p] = (long long)(unsigned)s |
                  ((long long)(unsigned)__float_as_uint(w) << 32);
    }
    __syncthreads();
    if (t < 128) {
        int node = node0 + t;
        if (node < N) {
            int endp = pbase + pexcl[t] + padarr[t];
            long long rec = (long long)(unsigned)node;  // hi=0 -> w=0.0f
            for (int p = cur[t]; p < endp; ++p) csr2[p] = rec;
        }
    }
}

// ---- wprep: weights -> fp16 [out-col][K], bias2 = bmu||bls ------------------
__global__ __launch_bounds__(256) void wprep(const float* __restrict__ W1,
                                             const float* __restrict__ Wmu,
                                             const float* __restrict__ bmu,
                                             const float* __restrict__ Wls,
                                             const float* __restrict__ bls,
                                             __half* __restrict__ Wt1,
                                             __half* __restrict__ Wt2,
                                             float* __restrict__ bias2) {
    int i = blockIdx.x * 256 + threadIdx.x;
    if (i < 16384) {
        int n = i >> 7, k = i & 127;
        Wt1[i] = __float2half_rn(W1[k * 128 + n]);
        float v = (n < 64) ? Wmu[k * 64 + n] : Wls[k * 64 + (n - 64)];
        Wt2[i] = __float2half_rn(v);
    }
    if (i < 64) {
        bias2[i] = bmu[i];
        bias2[64 + i] = bls[i];
    }
}

// ---- MFMA GEMM: C_sliced[s][M][16](fp16) = A[M,128] @ Bt^T ------------------
// Bt fp16 [128][128]: row = out-col, K contiguous. 256 thr, 4 waves x 32 rows.
// AF32=1: A = f32 [M][128] rows (input x). AF32=0: A = slice-major fp16.
// C always slice-major: Cs[((size_t)ct*M? no: ct*N + row)*16 + lr].
template <int AF32>
__global__ __launch_bounds__(256) void gemm_mfma(const void* __restrict__ Av, int M,
                                                 const __half* __restrict__ Bt,
                                                 __half* __restrict__ C) {
    __shared__ __half Bs[128][136];
    int tid = threadIdx.x;
#pragma unroll
    for (int i = 0; i < 8; ++i) {
        int idx = tid + i * 256;
        int r = idx >> 4;
        int c8 = (idx & 15) << 3;
        *(float4*)&Bs[r][c8] = *(const float4*)(Bt + r * 128 + c8);
    }
    __syncthreads();
    int wave = tid >> 6, lane = tid & 63;
    int lr = lane & 15, lk = lane >> 4;
    int row0 = blockIdx.x * 128 + wave * 32;

    f32x4_t acc[2][8];
#pragma unroll
    for (int rt = 0; rt < 2; ++rt)
#pragma unroll
        for (int ct = 0; ct < 8; ++ct) acc[rt][ct] = (f32x4_t)0.0f;

    half8_t afr[2][4];
#pragma unroll
    for (int rt = 0; rt < 2; ++rt) {
        int row = row0 + rt * 16 + lr;
        if (row >= M) row = M - 1;
        if (AF32) {
            const float* A = (const float*)Av + (size_t)row * 128;
#pragma unroll
            for (int ks = 0; ks < 4; ++ks) {
                float4 v0 = *(const float4*)(A + ks * 32 + lk * 8);
                float4 v1 = *(const float4*)(A + ks * 32 + lk * 8 + 4);
                half8_t f;
                f[0] = (_Float16)v0.x; f[1] = (_Float16)v0.y;
                f[2] = (_Float16)v0.z; f[3] = (_Float16)v0.w;
                f[4] = (_Float16)v1.x; f[5] = (_Float16)v1.y;
                f[6] = (_Float16)v1.z; f[7] = (_Float16)v1.w;
                afr[rt][ks] = f;
            }
        } else {
            const __half* A = (const __half*)Av;
#pragma unroll
            for (int ks = 0; ks < 4; ++ks) {
                int slice = 2 * ks + (lk >> 1);
                afr[rt][ks] = *(const half8_t*)(A + ((size_t)slice * M + row) * 16 + (lk & 1) * 8);
            }
        }
    }
#pragma unroll
    for (int ks = 0; ks < 4; ++ks)
#pragma unroll
        for (int ct = 0; ct < 8; ++ct) {
            half8_t b = *(const half8_t*)&Bs[ct * 16 + lr][ks * 32 + lk * 8];
            acc[0][ct] = __builtin_amdgcn_mfma_f32_16x16x32_f16(afr[0][ks], b, acc[0][ct], 0, 0, 0);
            acc[1][ct] = __builtin_amdgcn_mfma_f32_16x16x32_f16(afr[1][ks], b, acc[1][ct], 0, 0, 0);
        }
    // C layout (16x16x32_f16): col = lane&15, row = (lane>>4)*4 + reg
#pragma unroll
    for (int rt = 0; rt < 2; ++rt)
#pragma unroll
        for (int r = 0; r < 4; ++r) {
            int row = row0 + rt * 16 + lk * 4 + r;
            if (row < M) {
#pragma unroll
                for (int ct = 0; ct < 8; ++ct)
                    C[((size_t)ct * M + row) * 16 + lr] = __float2half_rn(acc[rt][ct][r]);
            }
        }
}

// ---- gather_slice: channel-sliced gather, XCD-L2-resident -------------------
// Grid: chunk*8 + slice; blockIdx%8 -> slice (-> XCD via round-robin dispatch).
// Block: 128-node chunk for its 16-channel slice. Wave: 2 nodes x 16 slots x
// 2 ch-lanes; one 16B load/lane = 32 rows per instruction. Self-loop and pads
// are ordinary records. Butterfly-reduce over slot lanes (xor 2,4,8,16).
// MODE 0: out = relu(acc + bias) -> fp16 slice-major [s][N][16]
// MODE 1: out = acc + bias       -> f32 mu [N][64] || logstd [N][64]
template <int MODE>
__global__ __launch_bounds__(256) void gather_slice(const __half* __restrict__ hs,
                                                    const int* __restrict__ row_ptr,
                                                    const long long* __restrict__ csr2,
                                                    const float* __restrict__ bias,
                                                    void* __restrict__ outv, int N) {
    int b = blockIdx.x;
    int s = b & 7;
    int node0 = (b >> 3) << 7;
    int tid = threadIdx.x;
    int wave = tid >> 6, lane = tid & 63;
    int nd = lane >> 5;
    int slot = (lane >> 1) & 15;
    int ch = lane & 1;
    const __half* hb = hs + (size_t)s * N * 16;
    float bs[8];
    {
        const float4* bp = (const float4*)(bias + s * 16 + ch * 8);
        float4 b0 = bp[0], b1v = bp[1];
        bs[0] = b0.x; bs[1] = b0.y; bs[2] = b0.z; bs[3] = b0.w;
        bs[4] = b1v.x; bs[5] = b1v.y; bs[6] = b1v.z; bs[7] = b1v.w;
    }
#pragma unroll 1
    for (int pr = wave; pr < 64; pr += 4) {
        int nodeA = node0 + pr * 2;
        if (nodeA >= N) break;
        int bval = (nodeA + 1) < N;
        int wid = nodeA + (nd & bval);
        int beg = row_ptr[wid];
        int end = row_ptr[wid + 1];
        float acc[8] = {};
        long long e = csr2[beg + slot];   // list length always >= 16
#pragma unroll 1
        for (int j = beg; j < end; j += 16) {
            int jn = j + 16;
            long long en = 0;
            if (jn < end) en = csr2[jn + slot];  // prefetch next quad-row
            int src = (int)(unsigned)(e & 0xffffffffLL);
            float wgt = __uint_as_float((unsigned)((unsigned long long)e >> 32));
            float4 raw = *(const float4*)(hb + (size_t)src * 16 + ch * 8);
            const __half2* hp = (const __half2*)&raw;
#pragma unroll
            for (int q = 0; q < 4; ++q) {
                float2 f = __half22float2(hp[q]);
                acc[2 * q]     = fmaf(wgt, f.x, acc[2 * q]);
                acc[2 * q + 1] = fmaf(wgt, f.y, acc[2 * q + 1]);
            }
            e = en;
        }
#pragma unroll
        for (int q = 0; q < 8; ++q) {
            acc[q] += __shfl_xor(acc[q], 2, 64);
            acc[q] += __shfl_xor(acc[q], 4, 64);
            acc[q] += __shfl_xor(acc[q], 8, 64);
            acc[q] += __shfl_xor(acc[q], 16, 64);
        }
        if (slot == 0 && (nd == 0 || bval)) {
            if (MODE == 0) {
#pragma unroll
                for (int q = 0; q < 8; ++q) acc[q] = fmaxf(acc[q] + bs[q], 0.0f);
                union { __half2 h2[4]; float4 f4; } u;
                u.h2[0] = __floats2half2_rn(acc[0], acc[1]);
                u.h2[1] = __floats2half2_rn(acc[2], acc[3]);
                u.h2[2] = __floats2half2_rn(acc[4], acc[5]);
                u.h2[3] = __floats2half2_rn(acc[6], acc[7]);
                *(float4*)((__half*)outv + ((size_t)s * N + wid) * 16 + ch * 8) = u.f4;
            } else {
#pragma unroll
                for (int q = 0; q < 8; ++q) acc[q] += bs[q];
                int c0 = s * 16 + ch * 8;
                float* mu = (float*)outv;
                float* ls = mu + (size_t)N * 64;
                float* dst = (c0 < 64) ? (mu + (size_t)wid * 64 + c0)
                                       : (ls + (size_t)wid * 64 + (c0 - 64));
                ((float4*)dst)[0] = make_float4(acc[0], acc[1], acc[2], acc[3]);
                ((float4*)dst)[1] = make_float4(acc[4], acc[5], acc[6], acc[7]);
            }
        }
    }
}

extern "C" void kernel_launch(void* const* d_in, const int* in_sizes, int n_in,
                              void* d_out, int out_size, void* d_ws, size_t ws_size,
                              hipStream_t stream) {
    const float* x   = (const float*)d_in[0];
    const int*  eidx = (const int*)d_in[1];
    const float* W1  = (const float*)d_in[2];
    const float* b1  = (const float*)d_in[3];
    const float* Wmu = (const float*)d_in[4];
    const float* bmu = (const float*)d_in[5];
    const float* Wls = (const float*)d_in[6];
    const float* bls = (const float*)d_in[7];
    float* out = (float*)d_out;

    const int N = in_sizes[0] / 128;  // 100000
    const int E = in_sizes[1] / 2;    // 1600000
    const int* src = eidx;
    const int* dst = eidx + E;

    int shift = 0;
    while (((N - 1) >> shift) >= NBUCKET) ++shift;  // N=100000 -> 7 (bw=128)
    int chunk = (E + NPB - 1) / NPB;

    char* w = (char*)d_ws;
    size_t off = 0;
    auto alloc = [&](size_t bytes) {
        void* p = w + off;
        off += (bytes + 255) & ~(size_t)255;
        return p;
    };
    // persistent region
    int*       row_ptr      = (int*)alloc((size_t)(N + 1) * 4);
    float*     dinv         = (float*)alloc((size_t)N * 4);
    int*       bucket_total = (int*)alloc(NBUCKET * 4);
    int*       bucket_base  = (int*)alloc(NBUCKET * 4);
    int*       padded_total = (int*)alloc(NBUCKET * 4);
    int*       padded_base  = (int*)alloc(NBUCKET * 4);
    __half*    Wt1          = (__half*)alloc(16384 * 2);
    __half*    Wt2          = (__half*)alloc(16384 * 2);
    float*     bias2        = (float*)alloc(128 * 4);
    size_t csr_cap = (size_t)E + 40u * (size_t)N + 64;  // self + pair-pad bound
    long long* csr2         = (long long*)alloc(csr_cap * 8);
    __half*    h1           = (__half*)alloc((size_t)N * 128 * 2);
    // region D: partition buffers; then h (fp16), then p (fp16) reuse it
    size_t Dstart = off;
    int*       degi     = (int*)alloc((size_t)N * 4);
    int*       blk_hist = (int*)alloc((size_t)NPB * NBUCKET * 4);
    int*       blk_base = (int*)alloc((size_t)NPB * NBUCKET * 4);
    long long* part     = (long long*)alloc((size_t)E * 8);
    size_t Dearly_end = off;
    __half* h = (__half*)(w + Dstart);
    __half* p = (__half*)(w + Dstart);
    size_t Dend = Dstart + (size_t)N * 128 * 2;
    off = (Dearly_end > Dend) ? Dearly_end : Dend;
    if (off > ws_size) return;  // workspace too small: fail cleanly

    // ---- weight prep + partition + fused CSR build ----
    wprep<<<64, 256, 0, stream>>>(W1, Wmu, bmu, Wls, bls, Wt1, Wt2, bias2);
    hist_pass<<<NPB, 256, 0, stream>>>(dst, E, chunk, shift, blk_hist);
    col_scan<<<NBUCKET, 256, 0, stream>>>(blk_hist, blk_base, bucket_total);
    scan_bucket<<<1, 256, 0, stream>>>(bucket_total, bucket_base);
    scatter_pass<<<NPB, 256, 0, stream>>>(src, dst, E, chunk, shift, bucket_base, blk_base, part);
    bucket_count<<<NBUCKET, 256, 0, stream>>>(part, bucket_base, bucket_total, N, shift,
                                              degi, dinv, padded_total);
    scan_bucket<<<1, 256, 0, stream>>>(padded_total, padded_base);
    bucket_fill<<<NBUCKET, 256, 0, stream>>>(part, bucket_base, bucket_total, padded_base,
                                             degi, dinv, N, shift, row_ptr, csr2);

    // ---- compute ----
    int gemm_blocks = (N + 127) / 128;
    int gblocks = ((N + 127) / 128) * 8;  // chunks x 8 slices
    // h = x @ W1  (fp16, slice-major)
    gemm_mfma<1><<<gemm_blocks, 256, 0, stream>>>(x, N, Wt1, h);
    // h1 = relu(A @ h + b1)  (fp16, slice-major)
    gather_slice<0><<<gblocks, 256, 0, stream>>>(h, row_ptr, csr2, b1, h1, N);
    // p = h1 @ [Wmu|Wls]  (fp16, slice-major)
    gemm_mfma<0><<<gemm_blocks, 256, 0, stream>>>(h1, N, Wt2, p);
    // mu|logstd = A @ p + bias2  -> d_out (f32 halves)
    gather_slice<1><<<gblocks, 256, 0, stream>>>(p, row_ptr, csr2, bias2, out, N);
}

// Round 9
// 236.315 us; speedup vs baseline: 1.7038x; 1.7038x over previous
//
#include <hip/hip_runtime.h>
#include <hip/hip_fp16.h>

// ---------------------------------------------------------------------------
// VariationalGCNEncoder on MI355X  (R9 = R7 compute + consolidated partition)
//   prep_hist: wprep (64 blocks) + per-block bucket histogram (512 blocks)
//   col_scan:  per-bucket column scan of block histograms
//   scatter:   inline 1024-prefix scan (LDS) + scatter (dst,src) -> part[]
//   bucket_count: block-local base reduction + LDS node count -> degi/dinv
//   bucket_fill:  block-local base reductions + row_ptr + weighted csr2
//   h  = x @ W1                (MFMA fp16)
//   h1 = relu(A @ h + b1)      (gather_pair, 32 rows in flight, fp16)
//   p  = h1 @ [Wmu|Wls]        (MFMA fp16)
//   mu|logstd = A @ p + bias2  (gather_pair, f32 split out to d_out)
// Gathers are at the 8-XCD x 25.6MB L2-replication floor (~3.5 TB/s plateau,
// MLP-saturated at 16+ rows in flight) -- left untouched from R7.
// ---------------------------------------------------------------------------

#define NBUCKET 1024
#define NPB 512  // partition blocks; chunk = ceil(E/NPB)

typedef _Float16 half8_t __attribute__((ext_vector_type(8)));
typedef float f32x4_t __attribute__((ext_vector_type(4)));

// ---- pass 1: per-block bucket histogram, + weight prep in spare blocks -----
__global__ __launch_bounds__(256) void prep_hist(const int* __restrict__ dst, int E,
                                                 int chunk, int shift,
                                                 int* __restrict__ blk_hist,
                                                 const float* __restrict__ W1,
                                                 const float* __restrict__ Wmu,
                                                 const float* __restrict__ bmu,
                                                 const float* __restrict__ Wls,
                                                 const float* __restrict__ bls,
                                                 __half* __restrict__ Wt1,
                                                 __half* __restrict__ Wt2,
                                                 float* __restrict__ bias2) {
    int b = blockIdx.x;
    if (b >= NPB) {
        int i = (b - NPB) * 256 + threadIdx.x;
        if (i < 16384) {
            int n = i >> 7, k = i & 127;
            Wt1[i] = __float2half_rn(W1[k * 128 + n]);
            float v = (n < 64) ? Wmu[k * 64 + n] : Wls[k * 64 + (n - 64)];
            Wt2[i] = __float2half_rn(v);
        }
        if (i < 64) {
            bias2[i] = bmu[i];
            bias2[64 + i] = bls[i];
        }
        return;
    }
    __shared__ int hist[NBUCKET];
    for (int i = threadIdx.x; i < NBUCKET; i += 256) hist[i] = 0;
    __syncthreads();
    int beg = b * chunk;
    int end = beg + chunk; if (end > E) end = E;
    for (int i = beg + threadIdx.x; i < end; i += 256)
        atomicAdd(&hist[dst[i] >> shift], 1);
    __syncthreads();
    for (int i = threadIdx.x; i < NBUCKET; i += 256)
        blk_hist[(size_t)b * NBUCKET + i] = hist[i];
}

// ---- pass 2: per-bucket column scan (one block per bucket) -----------------
__global__ __launch_bounds__(256) void col_scan(const int* __restrict__ blk_hist,
                                                int* __restrict__ blk_base,
                                                int* __restrict__ bucket_total) {
    __shared__ int sh[256];
    int q = blockIdx.x, t = threadIdx.x;
    int v0 = blk_hist[(size_t)(2 * t) * NBUCKET + q];
    int v1 = blk_hist[(size_t)(2 * t + 1) * NBUCKET + q];
    int s = v0 + v1;
    sh[t] = s;
    __syncthreads();
    for (int off = 1; off < 256; off <<= 1) {
        int x = (t >= off) ? sh[t - off] : 0;
        __syncthreads();
        sh[t] += x;
        __syncthreads();
    }
    int pre = sh[t] - s;
    blk_base[(size_t)(2 * t) * NBUCKET + q] = pre;
    blk_base[(size_t)(2 * t + 1) * NBUCKET + q] = pre + v0;
    if (t == 255) bucket_total[q] = sh[255];
}

// block-local reduction: sum of total[0..b) using 256 threads + LDS
__device__ __forceinline__ int partial_base(const int* __restrict__ total, int b,
                                            int* sh /*256*/) {
    int t = threadIdx.x;
    int s = 0;
    for (int i = t; i < b; i += 256) s += total[i];
    sh[t] = s;
    __syncthreads();
    for (int off = 128; off >= 1; off >>= 1) {
        if (t < off) sh[t] += sh[t + off];
        __syncthreads();
    }
    int r = sh[0];
    __syncthreads();
    return r;
}

// ---- pass 3: inline full prefix + scatter (dst,src) into part[] -------------
__global__ __launch_bounds__(256) void scatter_pass(const int* __restrict__ src,
                                                    const int* __restrict__ dst, int E,
                                                    int chunk, int shift,
                                                    const int* __restrict__ bucket_total,
                                                    const int* __restrict__ blk_base,
                                                    long long* __restrict__ part) {
    __shared__ int cur[NBUCKET];
    __shared__ int sh[256];
    int b = blockIdx.x, t = threadIdx.x;
    // exclusive prefix of bucket_total into cur
    {
        int idx0 = t * 4;
        int v[4];
#pragma unroll
        for (int k = 0; k < 4; ++k) v[k] = bucket_total[idx0 + k];
        int s = v[0] + v[1] + v[2] + v[3];
        sh[t] = s;
        __syncthreads();
        for (int off = 1; off < 256; off <<= 1) {
            int x = (t >= off) ? sh[t - off] : 0;
            __syncthreads();
            sh[t] += x;
            __syncthreads();
        }
        int run = sh[t] - s;
#pragma unroll
        for (int k = 0; k < 4; ++k) {
            cur[idx0 + k] = run;
            run += v[k];
        }
    }
    __syncthreads();
    for (int i = t; i < NBUCKET; i += 256)
        cur[i] += blk_base[(size_t)b * NBUCKET + i];
    __syncthreads();
    int beg = b * chunk;
    int end = beg + chunk; if (end > E) end = E;
    for (int i = beg + t; i < end; i += 256) {
        int d = dst[i], s = src[i];
        int q = d >> shift;
        int p = atomicAdd(&cur[q], 1);
        part[p] = ((long long)(unsigned)d << 32) | (unsigned)s;
    }
}

// ---- bucket_count: local base + LDS count -> degi, dinv, padded total -------
__global__ __launch_bounds__(256) void bucket_count(const long long* __restrict__ part,
                                                    const int* __restrict__ bucket_total,
                                                    int N, int shift,
                                                    int* __restrict__ degi,
                                                    float* __restrict__ dinv,
                                                    int* __restrict__ padded_total) {
    __shared__ int cnt[128];
    __shared__ int sh[256];
    int b = blockIdx.x, t = threadIdx.x;
    int beg = partial_base(bucket_total, b, sh);
    int end = beg + bucket_total[b];
    if (t < 128) cnt[t] = 0;
    __syncthreads();
    int node0 = b << shift;
    for (int i = beg + t; i < end; i += 256) {
        int d = (int)((unsigned long long)part[i] >> 32);
        atomicAdd(&cnt[d - node0], 1);
    }
    __syncthreads();
    if (t < 128) {
        int node = node0 + t;
        int c = (node < N) ? cnt[t] : 0;
        if (node < N) {
            degi[node] = c;
            dinv[node] = rsqrtf((float)(c + 1));
        }
        sh[t] = c;
    }
    __syncthreads();
    int padded = 0;
    if (t < 128) {
        int node = node0 + t;
        if (node < N) {
            int mine = (sh[t] + 15) >> 4;
            int pi = t ^ 1;
            int pnode = node0 + pi;
            int theirs = (pnode < N) ? ((sh[pi] + 15) >> 4) : 0;
            int L = mine > theirs ? mine : theirs;
            padded = L << 4;
        }
    }
    __syncthreads();
    if (t < 128) sh[t] = padded; else if (t < 256) sh[t] = 0;
    __syncthreads();
    for (int off = 64; off >= 1; off >>= 1) {
        if (t < off) sh[t] += sh[t + off];
        __syncthreads();
    }
    if (t == 0) padded_total[b] = sh[0];
}

// ---- bucket_fill: local bases + row_ptr + weighted scatter into csr2 --------
__global__ __launch_bounds__(256) void bucket_fill(const long long* __restrict__ part,
                                                   const int* __restrict__ bucket_total,
                                                   const int* __restrict__ padded_total,
                                                   const int* __restrict__ degi,
                                                   const float* __restrict__ dinv,
                                                   int N, int shift,
                                                   int* __restrict__ row_ptr,
                                                   long long* __restrict__ csr2) {
    __shared__ int sh[256];
    __shared__ int pexcl[128];
    __shared__ int padarr[128];
    __shared__ int cur[128];
    __shared__ float dvl[128];
    int b = blockIdx.x, t = threadIdx.x;
    int node0 = b << shift;
    int ebeg = partial_base(bucket_total, b, sh);
    int eend = ebeg + bucket_total[b];
    int pbase = partial_base(padded_total, b, sh);

    if (t < 128) {
        int node = node0 + t;
        int deg = (node < N) ? degi[node] : 0;
        dvl[t] = (node < N) ? dinv[node] : 0.0f;
        sh[t] = deg;
    }
    __syncthreads();
    int padded = 0;
    if (t < 128) {
        int node = node0 + t;
        if (node < N) {
            int mine = (sh[t] + 15) >> 4;
            int pi = t ^ 1;
            int pnode = node0 + pi;
            int theirs = (pnode < N) ? ((sh[pi] + 15) >> 4) : 0;
            int L = mine > theirs ? mine : theirs;
            padded = L << 4;
        }
        padarr[t] = padded;
    }
    __syncthreads();
    if (t < 128) sh[t] = padded;
    __syncthreads();
    for (int off = 1; off < 128; off <<= 1) {
        int x = 0;
        if (t < 128 && t >= off) x = sh[t - off];
        __syncthreads();
        if (t < 128) sh[t] += x;
        __syncthreads();
    }
    if (t < 128) {
        int excl = sh[t] - padarr[t];
        pexcl[t] = excl;
        cur[t] = pbase + excl;
        int node = node0 + t;
        if (node < N) row_ptr[node] = pbase + excl;
    }
    __syncthreads();
    if (t == 0) {
        int boundary = node0 + 128;
        if (boundary > N) boundary = N;
        row_ptr[boundary] = pbase + sh[127];  // benign overlap with next bucket
    }
    for (int i = ebeg + t; i < eend; i += 256) {
        long long pr = part[i];
        int d = (int)((unsigned long long)pr >> 32);
        int s = (int)(unsigned)(pr & 0xffffffffLL);
        int dl = d - node0;
        int p = atomicAdd(&cur[dl], 1);
        float w = dinv[s] * dvl[dl];
        csr2[p] = (long long)(unsigned)s |
                  ((long long)(unsigned)__float_as_uint(w) << 32);
    }
    __syncthreads();
    if (t < 128) {
        int node = node0 + t;
        if (node < N) {
            int endp = pbase + pexcl[t] + padarr[t];
            long long rec = (long long)(unsigned)node;  // hi=0 -> w=0.0f
            for (int p = cur[t]; p < endp; ++p) csr2[p] = rec;
        }
    }
}

// ---- MFMA GEMM: C[M,128](fp16) = A[M,128] @ Bt^T ---------------------------
template <int AF32>
__global__ __launch_bounds__(256) void gemm_mfma(const void* __restrict__ Av, int M,
                                                 const __half* __restrict__ Bt,
                                                 __half* __restrict__ C) {
    __shared__ __half Bs[128][136];
    int tid = threadIdx.x;
#pragma unroll
    for (int i = 0; i < 8; ++i) {
        int idx = tid + i * 256;
        int r = idx >> 4;
        int c8 = (idx & 15) << 3;
        *(float4*)&Bs[r][c8] = *(const float4*)(Bt + r * 128 + c8);
    }
    __syncthreads();
    int wave = tid >> 6, lane = tid & 63;
    int lr = lane & 15, lk = lane >> 4;
    int row0 = blockIdx.x * 128 + wave * 32;

    f32x4_t acc[2][8];
#pragma unroll
    for (int rt = 0; rt < 2; ++rt)
#pragma unroll
        for (int ct = 0; ct < 8; ++ct) acc[rt][ct] = (f32x4_t)0.0f;

    half8_t afr[2][4];
#pragma unroll
    for (int rt = 0; rt < 2; ++rt) {
        int row = row0 + rt * 16 + lr;
        if (row >= M) row = M - 1;
        if (AF32) {
            const float* A = (const float*)Av + (size_t)row * 128;
#pragma unroll
            for (int ks = 0; ks < 4; ++ks) {
                float4 v0 = *(const float4*)(A + ks * 32 + lk * 8);
                float4 v1 = *(const float4*)(A + ks * 32 + lk * 8 + 4);
                half8_t f;
                f[0] = (_Float16)v0.x; f[1] = (_Float16)v0.y;
                f[2] = (_Float16)v0.z; f[3] = (_Float16)v0.w;
                f[4] = (_Float16)v1.x; f[5] = (_Float16)v1.y;
                f[6] = (_Float16)v1.z; f[7] = (_Float16)v1.w;
                afr[rt][ks] = f;
            }
        } else {
            const __half* A = (const __half*)Av + (size_t)row * 128;
#pragma unroll
            for (int ks = 0; ks < 4; ++ks)
                afr[rt][ks] = *(const half8_t*)(A + ks * 32 + lk * 8);
        }
    }
#pragma unroll
    for (int ks = 0; ks < 4; ++ks)
#pragma unroll
        for (int ct = 0; ct < 8; ++ct) {
            half8_t b = *(const half8_t*)&Bs[ct * 16 + lr][ks * 32 + lk * 8];
            acc[0][ct] = __builtin_amdgcn_mfma_f32_16x16x32_f16(afr[0][ks], b, acc[0][ct], 0, 0, 0);
            acc[1][ct] = __builtin_amdgcn_mfma_f32_16x16x32_f16(afr[1][ks], b, acc[1][ct], 0, 0, 0);
        }
    // C layout (16x16x32_f16): col = lane&15, row = (lane>>4)*4 + reg
#pragma unroll
    for (int rt = 0; rt < 2; ++rt)
#pragma unroll
        for (int r = 0; r < 4; ++r) {
            int row = row0 + rt * 16 + lk * 4 + r;
            if (row < M) {
#pragma unroll
                for (int ct = 0; ct < 8; ++ct)
                    C[(size_t)row * 128 + ct * 16 + lr] = __float2half_rn(acc[rt][ct][r]);
            }
        }
}

// ---- gather: 2 nodes/wave, padded mask-free loop, e-prefetch pipeline -------
// MODE 0: out = relu(acc + bias) -> fp16 [n][128]
// MODE 1: out = acc + bias       -> f32 mu [n][64] || logstd [n][64]
template <int MODE>
__global__ __launch_bounds__(256) void gather_pair(const __half* __restrict__ h,
                                                   const float* __restrict__ dinv,
                                                   const int* __restrict__ row_ptr,
                                                   const long long* __restrict__ csr2,
                                                   const float* __restrict__ bias,
                                                   void* __restrict__ outv, int n) {
    int wv = (blockIdx.x * 256 + threadIdx.x) >> 6;
    int lane = threadIdx.x & 63;
    int nodeA = wv * 2;
    if (nodeA >= n) return;
    int half = lane >> 5;
    int grp2 = (lane >> 4) & 1;
    int cs = lane & 15;
    int bvalid = (nodeA + 1) < n;
    int wid = nodeA + (half & bvalid);
    float dv = dinv[wid];
    int beg = row_ptr[wid];
    int end = row_ptr[wid + 1];

    float acc[8];
    {
        float4 raw = *(const float4*)(h + (size_t)wid * 128 + cs * 8);
        const __half2* hp = (const __half2*)&raw;
        float sw = (grp2 == 0) ? dv * dv : 0.0f;
#pragma unroll
        for (int q = 0; q < 4; ++q) {
            float2 f = __half22float2(hp[q]);
            acc[2 * q]     = sw * f.x;
            acc[2 * q + 1] = sw * f.y;
        }
    }

    long long e[8];
    if (beg < end) {
#pragma unroll
        for (int u = 0; u < 8; ++u) e[u] = csr2[beg + u * 2 + grp2];
    }
#pragma unroll 1
    for (int j = beg; j < end; j += 16) {
        int jn = j + 16;
        int jp = (jn < end) ? jn : beg;
        long long en[8];
#pragma unroll
        for (int u = 0; u < 8; ++u) en[u] = csr2[jp + u * 2 + grp2];
        float4 raw[8];
        float wgt[8];
#pragma unroll
        for (int u = 0; u < 8; ++u) {
            int s = (int)(unsigned)(e[u] & 0xffffffffLL);
            wgt[u] = __uint_as_float((unsigned)((unsigned long long)e[u] >> 32));
            raw[u] = *(const float4*)(h + (size_t)s * 128 + cs * 8);
        }
#pragma unroll
        for (int u = 0; u < 8; ++u) {
            const __half2* hp = (const __half2*)&raw[u];
#pragma unroll
            for (int q = 0; q < 4; ++q) {
                float2 f = __half22float2(hp[q]);
                acc[2 * q]     = fmaf(wgt[u], f.x, acc[2 * q]);
                acc[2 * q + 1] = fmaf(wgt[u], f.y, acc[2 * q + 1]);
            }
        }
#pragma unroll
        for (int u = 0; u < 8; ++u) e[u] = en[u];
    }

#pragma unroll
    for (int q = 0; q < 8; ++q) acc[q] += __shfl_xor(acc[q], 16, 64);

    {
        const float4* bp = (const float4*)(bias + cs * 8);
        float4 b0 = bp[0], b1 = bp[1];
        if (MODE == 0) {
            acc[0] = fmaxf(acc[0] + b0.x, 0.0f);
            acc[1] = fmaxf(acc[1] + b0.y, 0.0f);
            acc[2] = fmaxf(acc[2] + b0.z, 0.0f);
            acc[3] = fmaxf(acc[3] + b0.w, 0.0f);
            acc[4] = fmaxf(acc[4] + b1.x, 0.0f);
            acc[5] = fmaxf(acc[5] + b1.y, 0.0f);
            acc[6] = fmaxf(acc[6] + b1.z, 0.0f);
            acc[7] = fmaxf(acc[7] + b1.w, 0.0f);
        } else {
            acc[0] += b0.x; acc[1] += b0.y; acc[2] += b0.z; acc[3] += b0.w;
            acc[4] += b1.x; acc[5] += b1.y; acc[6] += b1.z; acc[7] += b1.w;
        }
    }

    if ((lane & 31) < 16 && (half == 0 || bvalid)) {
        if (MODE == 0) {
            union { __half2 h2[4]; float4 f4; } u;
            u.h2[0] = __floats2half2_rn(acc[0], acc[1]);
            u.h2[1] = __floats2half2_rn(acc[2], acc[3]);
            u.h2[2] = __floats2half2_rn(acc[4], acc[5]);
            u.h2[3] = __floats2half2_rn(acc[6], acc[7]);
            *(float4*)((__half*)outv + (size_t)wid * 128 + cs * 8) = u.f4;
        } else {
            float* mu = (float*)outv;
            float* ls = mu + (size_t)n * 64;
            float* op = (cs < 8) ? (mu + (size_t)wid * 64 + cs * 8)
                                 : (ls + (size_t)wid * 64 + (cs - 8) * 8);
            ((float4*)op)[0] = make_float4(acc[0], acc[1], acc[2], acc[3]);
            ((float4*)op)[1] = make_float4(acc[4], acc[5], acc[6], acc[7]);
        }
    }
}

extern "C" void kernel_launch(void* const* d_in, const int* in_sizes, int n_in,
                              void* d_out, int out_size, void* d_ws, size_t ws_size,
                              hipStream_t stream) {
    const float* x   = (const float*)d_in[0];
    const int*  eidx = (const int*)d_in[1];
    const float* W1  = (const float*)d_in[2];
    const float* b1  = (const float*)d_in[3];
    const float* Wmu = (const float*)d_in[4];
    const float* bmu = (const float*)d_in[5];
    const float* Wls = (const float*)d_in[6];
    const float* bls = (const float*)d_in[7];
    float* out = (float*)d_out;

    const int N = in_sizes[0] / 128;  // 100000
    const int E = in_sizes[1] / 2;    // 1600000
    const int* src = eidx;
    const int* dst = eidx + E;

    int shift = 0;
    while (((N - 1) >> shift) >= NBUCKET) ++shift;  // N=100000 -> 7 (bw=128)
    int chunk = (E + NPB - 1) / NPB;

    char* w = (char*)d_ws;
    size_t off = 0;
    auto alloc = [&](size_t bytes) {
        void* p = w + off;
        off += (bytes + 255) & ~(size_t)255;
        return p;
    };
    // persistent region
    int*       row_ptr      = (int*)alloc((size_t)(N + 1) * 4);
    float*     dinv         = (float*)alloc((size_t)N * 4);
    int*       bucket_total = (int*)alloc(NBUCKET * 4);
    int*       padded_total = (int*)alloc(NBUCKET * 4);
    __half*    Wt1          = (__half*)alloc(16384 * 2);
    __half*    Wt2          = (__half*)alloc(16384 * 2);
    float*     bias2        = (float*)alloc(128 * 4);
    size_t csr_cap = (size_t)E + 31u * (size_t)N + 64;  // pair-padding bound
    long long* csr2         = (long long*)alloc(csr_cap * 8);
    __half*    h1           = (__half*)alloc((size_t)N * 128 * 2);
    // region D: partition buffers; then h (fp16), then p (fp16) reuse it
    size_t Dstart = off;
    int*       degi     = (int*)alloc((size_t)N * 4);
    int*       blk_hist = (int*)alloc((size_t)NPB * NBUCKET * 4);
    int*       blk_base = (int*)alloc((size_t)NPB * NBUCKET * 4);
    long long* part     = (long long*)alloc((size_t)E * 8);
    size_t Dearly_end = off;
    __half* h = (__half*)(w + Dstart);
    __half* p = (__half*)(w + Dstart);
    size_t Dend = Dstart + (size_t)N * 128 * 2;
    off = (Dearly_end > Dend) ? Dearly_end : Dend;
    if (off > ws_size) return;  // workspace too small: fail cleanly

    // ---- partition + fused CSR build (5 dispatches) ----
    prep_hist<<<NPB + 64, 256, 0, stream>>>(dst, E, chunk, shift, blk_hist,
                                            W1, Wmu, bmu, Wls, bls, Wt1, Wt2, bias2);
    col_scan<<<NBUCKET, 256, 0, stream>>>(blk_hist, blk_base, bucket_total);
    scatter_pass<<<NPB, 256, 0, stream>>>(src, dst, E, chunk, shift,
                                          bucket_total, blk_base, part);
    bucket_count<<<NBUCKET, 256, 0, stream>>>(part, bucket_total, N, shift,
                                              degi, dinv, padded_total);
    bucket_fill<<<NBUCKET, 256, 0, stream>>>(part, bucket_total, padded_total,
                                             degi, dinv, N, shift, row_ptr, csr2);

    // ---- compute (4 dispatches) ----
    int gemm_blocks = (N + 127) / 128;
    int gblocks = (((N + 1) / 2) * 64 + 255) / 256;
    // h = x @ W1  (fp16)
    gemm_mfma<1><<<gemm_blocks, 256, 0, stream>>>(x, N, Wt1, h);
    // h1 = relu(A @ h + b1)  (fp16)
    gather_pair<0><<<gblocks, 256, 0, stream>>>(h, dinv, row_ptr, csr2, b1, h1, N);
    // p = h1 @ [Wmu|Wls]  (fp16)
    gemm_mfma<0><<<gemm_blocks, 256, 0, stream>>>(h1, N, Wt2, p);
    // mu|logstd = A @ p + bias2  -> d_out (f32 halves)
    gather_pair<1><<<gblocks, 256, 0, stream>>>(p, dinv, row_ptr, csr2, bias2, out, N);
}

// Round 10
// 227.749 us; speedup vs baseline: 1.7679x; 1.0376x over previous
//
#include <hip/hip_runtime.h>
#include <hip/hip_fp16.h>

// ---------------------------------------------------------------------------
// VariationalGCNEncoder on MI355X  (R10 = R9 + one-node-per-wave gathers)
//   prep_hist: wprep (64 blocks) + per-block bucket histogram (512 blocks)
//   col_scan:  per-bucket column scan of block histograms
//   scatter:   inline 1024-prefix scan (LDS) + scatter (dst,src) -> part[]
//   bucket_count: block-local base + LDS count -> degi/dinv, padded totals
//                 (slots = deg + 1 self-loop, padded to 16-multiples)
//   bucket_fill:  row_ptr + self record (w=dinv^2) + weighted edges + pads
//   h  = x @ W1                (MFMA fp16)
//   h1 = relu(A @ h + b1)      (gather_one: 1 node/wave, 16 rows in flight,
//   p  = h1 @ [Wmu|Wls]        (MFMA fp16)              mask-free, no dinv)
//   mu|logstd = A @ p + bias2  (gather_one, f32 split out to d_out)
// Gather rate history: 1-node waves 3.96 TB/s vs pair waves 3.59 TB/s at the
// same FETCH floor (198MB = 8 XCD x 25.6MB L2 replication) -> use 1-node.
// ---------------------------------------------------------------------------

#define NBUCKET 1024
#define NPB 512  // partition blocks; chunk = ceil(E/NPB)

typedef _Float16 half8_t __attribute__((ext_vector_type(8)));
typedef float f32x4_t __attribute__((ext_vector_type(4)));

// ---- pass 1: per-block bucket histogram, + weight prep in spare blocks -----
__global__ __launch_bounds__(256) void prep_hist(const int* __restrict__ dst, int E,
                                                 int chunk, int shift,
                                                 int* __restrict__ blk_hist,
                                                 const float* __restrict__ W1,
                                                 const float* __restrict__ Wmu,
                                                 const float* __restrict__ bmu,
                                                 const float* __restrict__ Wls,
                                                 const float* __restrict__ bls,
                                                 __half* __restrict__ Wt1,
                                                 __half* __restrict__ Wt2,
                                                 float* __restrict__ bias2) {
    int b = blockIdx.x;
    if (b >= NPB) {
        int i = (b - NPB) * 256 + threadIdx.x;
        if (i < 16384) {
            int n = i >> 7, k = i & 127;
            Wt1[i] = __float2half_rn(W1[k * 128 + n]);
            float v = (n < 64) ? Wmu[k * 64 + n] : Wls[k * 64 + (n - 64)];
            Wt2[i] = __float2half_rn(v);
        }
        if (i < 64) {
            bias2[i] = bmu[i];
            bias2[64 + i] = bls[i];
        }
        return;
    }
    __shared__ int hist[NBUCKET];
    for (int i = threadIdx.x; i < NBUCKET; i += 256) hist[i] = 0;
    __syncthreads();
    int beg = b * chunk;
    int end = beg + chunk; if (end > E) end = E;
    for (int i = beg + threadIdx.x; i < end; i += 256)
        atomicAdd(&hist[dst[i] >> shift], 1);
    __syncthreads();
    for (int i = threadIdx.x; i < NBUCKET; i += 256)
        blk_hist[(size_t)b * NBUCKET + i] = hist[i];
}

// ---- pass 2: per-bucket column scan (one block per bucket) -----------------
__global__ __launch_bounds__(256) void col_scan(const int* __restrict__ blk_hist,
                                                int* __restrict__ blk_base,
                                                int* __restrict__ bucket_total) {
    __shared__ int sh[256];
    int q = blockIdx.x, t = threadIdx.x;
    int v0 = blk_hist[(size_t)(2 * t) * NBUCKET + q];
    int v1 = blk_hist[(size_t)(2 * t + 1) * NBUCKET + q];
    int s = v0 + v1;
    sh[t] = s;
    __syncthreads();
    for (int off = 1; off < 256; off <<= 1) {
        int x = (t >= off) ? sh[t - off] : 0;
        __syncthreads();
        sh[t] += x;
        __syncthreads();
    }
    int pre = sh[t] - s;
    blk_base[(size_t)(2 * t) * NBUCKET + q] = pre;
    blk_base[(size_t)(2 * t + 1) * NBUCKET + q] = pre + v0;
    if (t == 255) bucket_total[q] = sh[255];
}

// block-local reduction: sum of total[0..b) using 256 threads + LDS
__device__ __forceinline__ int partial_base(const int* __restrict__ total, int b,
                                            int* sh /*256*/) {
    int t = threadIdx.x;
    int s = 0;
    for (int i = t; i < b; i += 256) s += total[i];
    sh[t] = s;
    __syncthreads();
    for (int off = 128; off >= 1; off >>= 1) {
        if (t < off) sh[t] += sh[t + off];
        __syncthreads();
    }
    int r = sh[0];
    __syncthreads();
    return r;
}

// ---- pass 3: inline full prefix + scatter (dst,src) into part[] -------------
__global__ __launch_bounds__(256) void scatter_pass(const int* __restrict__ src,
                                                    const int* __restrict__ dst, int E,
                                                    int chunk, int shift,
                                                    const int* __restrict__ bucket_total,
                                                    const int* __restrict__ blk_base,
                                                    long long* __restrict__ part) {
    __shared__ int cur[NBUCKET];
    __shared__ int sh[256];
    int b = blockIdx.x, t = threadIdx.x;
    {
        int idx0 = t * 4;
        int v[4];
#pragma unroll
        for (int k = 0; k < 4; ++k) v[k] = bucket_total[idx0 + k];
        int s = v[0] + v[1] + v[2] + v[3];
        sh[t] = s;
        __syncthreads();
        for (int off = 1; off < 256; off <<= 1) {
            int x = (t >= off) ? sh[t - off] : 0;
            __syncthreads();
            sh[t] += x;
            __syncthreads();
        }
        int run = sh[t] - s;
#pragma unroll
        for (int k = 0; k < 4; ++k) {
            cur[idx0 + k] = run;
            run += v[k];
        }
    }
    __syncthreads();
    for (int i = t; i < NBUCKET; i += 256)
        cur[i] += blk_base[(size_t)b * NBUCKET + i];
    __syncthreads();
    int beg = b * chunk;
    int end = beg + chunk; if (end > E) end = E;
    for (int i = beg + t; i < end; i += 256) {
        int d = dst[i], s = src[i];
        int q = d >> shift;
        int p = atomicAdd(&cur[q], 1);
        part[p] = ((long long)(unsigned)d << 32) | (unsigned)s;
    }
}

// ---- bucket_count: local base + LDS count -> degi, dinv, padded total -------
// Slots per node = deg + 1 (self-loop record), padded to 16-multiples.
__global__ __launch_bounds__(256) void bucket_count(const long long* __restrict__ part,
                                                    const int* __restrict__ bucket_total,
                                                    int N, int shift,
                                                    int* __restrict__ degi,
                                                    float* __restrict__ dinv,
                                                    int* __restrict__ padded_total) {
    __shared__ int cnt[128];
    __shared__ int sh[256];
    int b = blockIdx.x, t = threadIdx.x;
    int beg = partial_base(bucket_total, b, sh);
    int end = beg + bucket_total[b];
    if (t < 128) cnt[t] = 0;
    __syncthreads();
    int node0 = b << shift;
    for (int i = beg + t; i < end; i += 256) {
        int d = (int)((unsigned long long)part[i] >> 32);
        atomicAdd(&cnt[d - node0], 1);
    }
    __syncthreads();
    int padded = 0;
    if (t < 128) {
        int node = node0 + t;
        int c = (node < N) ? cnt[t] : 0;
        if (node < N) {
            degi[node] = c;
            dinv[node] = rsqrtf((float)(c + 1));
            padded = ((c + 16) >> 4) << 4;  // ceil((deg+1)/16)*16
        }
    }
    __syncthreads();
    if (t < 128) sh[t] = padded; else sh[t] = 0;
    __syncthreads();
    for (int off = 64; off >= 1; off >>= 1) {
        if (t < off) sh[t] += sh[t + off];
        __syncthreads();
    }
    if (t == 0) padded_total[b] = sh[0];
}

// ---- bucket_fill: row_ptr + self rec + weighted edges + pads into csr2 ------
__global__ __launch_bounds__(256) void bucket_fill(const long long* __restrict__ part,
                                                   const int* __restrict__ bucket_total,
                                                   const int* __restrict__ padded_total,
                                                   const int* __restrict__ degi,
                                                   const float* __restrict__ dinv,
                                                   int N, int shift,
                                                   int* __restrict__ row_ptr,
                                                   long long* __restrict__ csr2) {
    __shared__ int sh[256];
    __shared__ int pexcl[128];
    __shared__ int padarr[128];
    __shared__ int cur[128];
    __shared__ float dvl[128];
    int b = blockIdx.x, t = threadIdx.x;
    int node0 = b << shift;
    int ebeg = partial_base(bucket_total, b, sh);
    int eend = ebeg + bucket_total[b];
    int pbase = partial_base(padded_total, b, sh);

    int padded = 0;
    if (t < 128) {
        int node = node0 + t;
        int deg = (node < N) ? degi[node] : 0;
        dvl[t] = (node < N) ? dinv[node] : 0.0f;
        if (node < N) padded = ((deg + 16) >> 4) << 4;
        padarr[t] = padded;
    }
    __syncthreads();
    if (t < 128) sh[t] = padded;
    __syncthreads();
    for (int off = 1; off < 128; off <<= 1) {
        int x = 0;
        if (t < 128 && t >= off) x = sh[t - off];
        __syncthreads();
        if (t < 128) sh[t] += x;
        __syncthreads();
    }
    if (t < 128) {
        int excl = sh[t] - padarr[t];
        pexcl[t] = excl;
        int node = node0 + t;
        if (node < N) {
            row_ptr[node] = pbase + excl;
            // self-loop record first: (src=node, w=dinv^2)
            float ws = dvl[t] * dvl[t];
            csr2[pbase + excl] = (long long)(unsigned)node |
                                 ((long long)(unsigned)__float_as_uint(ws) << 32);
            cur[t] = pbase + excl + 1;
        } else {
            cur[t] = pbase + excl;
        }
    }
    __syncthreads();
    if (t == 0) {
        int boundary = node0 + 128;
        if (boundary > N) boundary = N;
        row_ptr[boundary] = pbase + sh[127];  // benign overlap with next bucket
    }
    for (int i = ebeg + t; i < eend; i += 256) {
        long long pr = part[i];
        int d = (int)((unsigned long long)pr >> 32);
        int s = (int)(unsigned)(pr & 0xffffffffLL);
        int dl = d - node0;
        int p = atomicAdd(&cur[dl], 1);
        float w = dinv[s] * dvl[dl];
        csr2[p] = (long long)(unsigned)s |
                  ((long long)(unsigned)__float_as_uint(w) << 32);
    }
    __syncthreads();
    if (t < 128) {
        int node = node0 + t;
        if (node < N) {
            int endp = pbase + pexcl[t] + padarr[t];
            long long rec = (long long)(unsigned)node;  // hi=0 -> w=0.0f
            for (int p = cur[t]; p < endp; ++p) csr2[p] = rec;
        }
    }
}

// ---- MFMA GEMM: C[M,128](fp16) = A[M,128] @ Bt^T ---------------------------
template <int AF32>
__global__ __launch_bounds__(256) void gemm_mfma(const void* __restrict__ Av, int M,
                                                 const __half* __restrict__ Bt,
                                                 __half* __restrict__ C) {
    __shared__ __half Bs[128][136];
    int tid = threadIdx.x;
#pragma unroll
    for (int i = 0; i < 8; ++i) {
        int idx = tid + i * 256;
        int r = idx >> 4;
        int c8 = (idx & 15) << 3;
        *(float4*)&Bs[r][c8] = *(const float4*)(Bt + r * 128 + c8);
    }
    __syncthreads();
    int wave = tid >> 6, lane = tid & 63;
    int lr = lane & 15, lk = lane >> 4;
    int row0 = blockIdx.x * 128 + wave * 32;

    f32x4_t acc[2][8];
#pragma unroll
    for (int rt = 0; rt < 2; ++rt)
#pragma unroll
        for (int ct = 0; ct < 8; ++ct) acc[rt][ct] = (f32x4_t)0.0f;

    half8_t afr[2][4];
#pragma unroll
    for (int rt = 0; rt < 2; ++rt) {
        int row = row0 + rt * 16 + lr;
        if (row >= M) row = M - 1;
        if (AF32) {
            const float* A = (const float*)Av + (size_t)row * 128;
#pragma unroll
            for (int ks = 0; ks < 4; ++ks) {
                float4 v0 = *(const float4*)(A + ks * 32 + lk * 8);
                float4 v1 = *(const float4*)(A + ks * 32 + lk * 8 + 4);
                half8_t f;
                f[0] = (_Float16)v0.x; f[1] = (_Float16)v0.y;
                f[2] = (_Float16)v0.z; f[3] = (_Float16)v0.w;
                f[4] = (_Float16)v1.x; f[5] = (_Float16)v1.y;
                f[6] = (_Float16)v1.z; f[7] = (_Float16)v1.w;
                afr[rt][ks] = f;
            }
        } else {
            const __half* A = (const __half*)Av + (size_t)row * 128;
#pragma unroll
            for (int ks = 0; ks < 4; ++ks)
                afr[rt][ks] = *(const half8_t*)(A + ks * 32 + lk * 8);
        }
    }
#pragma unroll
    for (int ks = 0; ks < 4; ++ks)
#pragma unroll
        for (int ct = 0; ct < 8; ++ct) {
            half8_t b = *(const half8_t*)&Bs[ct * 16 + lr][ks * 32 + lk * 8];
            acc[0][ct] = __builtin_amdgcn_mfma_f32_16x16x32_f16(afr[0][ks], b, acc[0][ct], 0, 0, 0);
            acc[1][ct] = __builtin_amdgcn_mfma_f32_16x16x32_f16(afr[1][ks], b, acc[1][ct], 0, 0, 0);
        }
    // C layout (16x16x32_f16): col = lane&15, row = (lane>>4)*4 + reg
#pragma unroll
    for (int rt = 0; rt < 2; ++rt)
#pragma unroll
        for (int r = 0; r < 4; ++r) {
            int row = row0 + rt * 16 + lk * 4 + r;
            if (row < M) {
#pragma unroll
                for (int ct = 0; ct < 8; ++ct)
                    C[(size_t)row * 128 + ct * 16 + lr] = __float2half_rn(acc[rt][ct][r]);
            }
        }
}

// ---- gather: one node per wave, mask-free padded rows, no dinv --------------
// 4 slot-groups x 16 ch-lanes; 4-unroll = 16 slots/iter, 16 rows in flight.
// Self-loop + pads are ordinary csr2 records. Reduce: xor 16, 32.
// MODE 0: out = relu(acc + bias) -> fp16 [n][128]
// MODE 1: out = acc + bias       -> f32 mu [n][64] || logstd [n][64]
template <int MODE>
__global__ __launch_bounds__(256) void gather_one(const __half* __restrict__ h,
                                                  const int* __restrict__ row_ptr,
                                                  const long long* __restrict__ csr2,
                                                  const float* __restrict__ bias,
                                                  void* __restrict__ outv, int n) {
    int wid = (blockIdx.x * 256 + threadIdx.x) >> 6;
    int lane = threadIdx.x & 63;
    if (wid >= n) return;
    int grp = lane >> 4;   // edge slot within each 16-slot quad
    int cs  = lane & 15;   // channel slice: 8 halves at cs*8
    int beg = row_ptr[wid];
    int end = row_ptr[wid + 1];   // length is a 16-multiple, >= 16

    float acc[8] = {};
#pragma unroll 1
    for (int j = beg; j < end; j += 16) {
        long long e[4];
#pragma unroll
        for (int u = 0; u < 4; ++u) e[u] = csr2[j + u * 4 + grp];
        float4 raw[4];
        float wgt[4];
#pragma unroll
        for (int u = 0; u < 4; ++u) {
            int s = (int)(unsigned)(e[u] & 0xffffffffLL);
            wgt[u] = __uint_as_float((unsigned)((unsigned long long)e[u] >> 32));
            raw[u] = *(const float4*)(h + (size_t)s * 128 + cs * 8);
        }
#pragma unroll
        for (int u = 0; u < 4; ++u) {
            const __half2* hp = (const __half2*)&raw[u];
#pragma unroll
            for (int q = 0; q < 4; ++q) {
                float2 f = __half22float2(hp[q]);
                acc[2 * q]     = fmaf(wgt[u], f.x, acc[2 * q]);
                acc[2 * q + 1] = fmaf(wgt[u], f.y, acc[2 * q + 1]);
            }
        }
    }

    // reduce the 4 slot-groups (lanes xor 16, 32)
#pragma unroll
    for (int q = 0; q < 8; ++q) {
        acc[q] += __shfl_xor(acc[q], 16, 64);
        acc[q] += __shfl_xor(acc[q], 32, 64);
    }

    {
        const float4* bp = (const float4*)(bias + cs * 8);
        float4 b0 = bp[0], b1 = bp[1];
        if (MODE == 0) {
            acc[0] = fmaxf(acc[0] + b0.x, 0.0f);
            acc[1] = fmaxf(acc[1] + b0.y, 0.0f);
            acc[2] = fmaxf(acc[2] + b0.z, 0.0f);
            acc[3] = fmaxf(acc[3] + b0.w, 0.0f);
            acc[4] = fmaxf(acc[4] + b1.x, 0.0f);
            acc[5] = fmaxf(acc[5] + b1.y, 0.0f);
            acc[6] = fmaxf(acc[6] + b1.z, 0.0f);
            acc[7] = fmaxf(acc[7] + b1.w, 0.0f);
        } else {
            acc[0] += b0.x; acc[1] += b0.y; acc[2] += b0.z; acc[3] += b0.w;
            acc[4] += b1.x; acc[5] += b1.y; acc[6] += b1.z; acc[7] += b1.w;
        }
    }

    if (lane < 16) {
        if (MODE == 0) {
            union { __half2 h2[4]; float4 f4; } u;
            u.h2[0] = __floats2half2_rn(acc[0], acc[1]);
            u.h2[1] = __floats2half2_rn(acc[2], acc[3]);
            u.h2[2] = __floats2half2_rn(acc[4], acc[5]);
            u.h2[3] = __floats2half2_rn(acc[6], acc[7]);
            *(float4*)((__half*)outv + (size_t)wid * 128 + cs * 8) = u.f4;
        } else {
            float* mu = (float*)outv;
            float* ls = mu + (size_t)n * 64;
            float* op = (cs < 8) ? (mu + (size_t)wid * 64 + cs * 8)
                                 : (ls + (size_t)wid * 64 + (cs - 8) * 8);
            ((float4*)op)[0] = make_float4(acc[0], acc[1], acc[2], acc[3]);
            ((float4*)op)[1] = make_float4(acc[4], acc[5], acc[6], acc[7]);
        }
    }
}

extern "C" void kernel_launch(void* const* d_in, const int* in_sizes, int n_in,
                              void* d_out, int out_size, void* d_ws, size_t ws_size,
                              hipStream_t stream) {
    const float* x   = (const float*)d_in[0];
    const int*  eidx = (const int*)d_in[1];
    const float* W1  = (const float*)d_in[2];
    const float* b1  = (const float*)d_in[3];
    const float* Wmu = (const float*)d_in[4];
    const float* bmu = (const float*)d_in[5];
    const float* Wls = (const float*)d_in[6];
    const float* bls = (const float*)d_in[7];
    float* out = (float*)d_out;

    const int N = in_sizes[0] / 128;  // 100000
    const int E = in_sizes[1] / 2;    // 1600000
    const int* src = eidx;
    const int* dst = eidx + E;

    int shift = 0;
    while (((N - 1) >> shift) >= NBUCKET) ++shift;  // N=100000 -> 7 (bw=128)
    int chunk = (E + NPB - 1) / NPB;

    char* w = (char*)d_ws;
    size_t off = 0;
    auto alloc = [&](size_t bytes) {
        void* p = w + off;
        off += (bytes + 255) & ~(size_t)255;
        return p;
    };
    // persistent region
    int*       row_ptr      = (int*)alloc((size_t)(N + 1) * 4);
    float*     dinv         = (float*)alloc((size_t)N * 4);
    int*       bucket_total = (int*)alloc(NBUCKET * 4);
    int*       padded_total = (int*)alloc(NBUCKET * 4);
    __half*    Wt1          = (__half*)alloc(16384 * 2);
    __half*    Wt2          = (__half*)alloc(16384 * 2);
    float*     bias2        = (float*)alloc(128 * 4);
    size_t csr_cap = (size_t)E + 17u * (size_t)N + 64;  // self + per-node pad
    long long* csr2         = (long long*)alloc(csr_cap * 8);
    __half*    h1           = (__half*)alloc((size_t)N * 128 * 2);
    // region D: partition buffers; then h (fp16), then p (fp16) reuse it
    size_t Dstart = off;
    int*       degi     = (int*)alloc((size_t)N * 4);
    int*       blk_hist = (int*)alloc((size_t)NPB * NBUCKET * 4);
    int*       blk_base = (int*)alloc((size_t)NPB * NBUCKET * 4);
    long long* part     = (long long*)alloc((size_t)E * 8);
    size_t Dearly_end = off;
    __half* h = (__half*)(w + Dstart);
    __half* p = (__half*)(w + Dstart);
    size_t Dend = Dstart + (size_t)N * 128 * 2;
    off = (Dearly_end > Dend) ? Dearly_end : Dend;
    if (off > ws_size) return;  // workspace too small: fail cleanly

    // ---- partition + fused CSR build (5 dispatches) ----
    prep_hist<<<NPB + 64, 256, 0, stream>>>(dst, E, chunk, shift, blk_hist,
                                            W1, Wmu, bmu, Wls, bls, Wt1, Wt2, bias2);
    col_scan<<<NBUCKET, 256, 0, stream>>>(blk_hist, blk_base, bucket_total);
    scatter_pass<<<NPB, 256, 0, stream>>>(src, dst, E, chunk, shift,
                                          bucket_total, blk_base, part);
    bucket_count<<<NBUCKET, 256, 0, stream>>>(part, bucket_total, N, shift,
                                              degi, dinv, padded_total);
    bucket_fill<<<NBUCKET, 256, 0, stream>>>(part, bucket_total, padded_total,
                                             degi, dinv, N, shift, row_ptr, csr2);

    // ---- compute (4 dispatches) ----
    int gemm_blocks = (N + 127) / 128;
    int gblocks = ((size_t)N * 64 + 255) / 256;
    // h = x @ W1  (fp16)
    gemm_mfma<1><<<gemm_blocks, 256, 0, stream>>>(x, N, Wt1, h);
    // h1 = relu(A @ h + b1)  (fp16)
    gather_one<0><<<gblocks, 256, 0, stream>>>(h, row_ptr, csr2, b1, h1, N);
    // p = h1 @ [Wmu|Wls]  (fp16)
    gemm_mfma<0><<<gemm_blocks, 256, 0, stream>>>(h1, N, Wt2, p);
    // mu|logstd = A @ p + bias2  -> d_out (f32 halves)
    gather_one<1><<<gblocks, 256, 0, stream>>>(p, row_ptr, csr2, bias2, out, N);
}

// Round 12
// 222.498 us; speedup vs baseline: 1.8096x; 1.0236x over previous
//
#include <hip/hip_runtime.h>
#include <hip/hip_fp16.h>

// ---------------------------------------------------------------------------
// VariationalGCNEncoder on MI355X  (R12 = R11 with nt-store type fix)
//   prep_hist: wprep (64 blocks) + per-block bucket histogram (256 blocks)
//   col_scan:  per-bucket column scan of block histograms (1 val/thread)
//   scatter:   inline 1024-prefix scan (LDS) + scatter (dst,src) -> part[]
//   bucket_count: block-local base + LDS count -> degi/dinv, padded totals
//   bucket_fill:  row_ptr + self record (w=dinv^2) + weighted edges + pads
//   h  = x @ W1                (MFMA fp16)
//   h1 = relu(A @ h + b1)      (gather_one, 16 rows in flight, mask-free)
//   p  = h1 @ [Wmu|Wls]        (MFMA fp16)
//   mu|logstd = A @ p + bias2  (gather_one, f32 split out, nontemporal)
// Gathers pinned at LLC random-access plateau (3.8-4.0 TB/s, FETCH = 8-XCD
// replication floor); this round targets the partition/write tail only.
// ---------------------------------------------------------------------------

#define NBUCKET 1024
#define NPB 256  // partition blocks; chunk = ceil(E/NPB)

typedef _Float16 half8_t __attribute__((ext_vector_type(8)));
typedef float f32x4_t __attribute__((ext_vector_type(4)));

// ---- pass 1: per-block bucket histogram, + weight prep in spare blocks -----
__global__ __launch_bounds__(256) void prep_hist(const int* __restrict__ dst, int E,
                                                 int chunk, int shift,
                                                 int* __restrict__ blk_hist,
                                                 const float* __restrict__ W1,
                                                 const float* __restrict__ Wmu,
                                                 const float* __restrict__ bmu,
                                                 const float* __restrict__ Wls,
                                                 const float* __restrict__ bls,
                                                 __half* __restrict__ Wt1,
                                                 __half* __restrict__ Wt2,
                                                 float* __restrict__ bias2) {
    int b = blockIdx.x;
    if (b >= NPB) {
        int i = (b - NPB) * 256 + threadIdx.x;
        if (i < 16384) {
            int n = i >> 7, k = i & 127;
            Wt1[i] = __float2half_rn(W1[k * 128 + n]);
            float v = (n < 64) ? Wmu[k * 64 + n] : Wls[k * 64 + (n - 64)];
            Wt2[i] = __float2half_rn(v);
        }
        if (i < 64) {
            bias2[i] = bmu[i];
            bias2[64 + i] = bls[i];
        }
        return;
    }
    __shared__ int hist[NBUCKET];
    for (int i = threadIdx.x; i < NBUCKET; i += 256) hist[i] = 0;
    __syncthreads();
    int beg = b * chunk;
    int end = beg + chunk; if (end > E) end = E;
    for (int i = beg + threadIdx.x; i < end; i += 256)
        atomicAdd(&hist[dst[i] >> shift], 1);
    __syncthreads();
    for (int i = threadIdx.x; i < NBUCKET; i += 256)
        blk_hist[(size_t)b * NBUCKET + i] = hist[i];
}

// ---- pass 2: per-bucket column scan (one block per bucket, NPB=256) --------
__global__ __launch_bounds__(256) void col_scan(const int* __restrict__ blk_hist,
                                                int* __restrict__ blk_base,
                                                int* __restrict__ bucket_total) {
    __shared__ int sh[256];
    int q = blockIdx.x, t = threadIdx.x;
    int v = blk_hist[(size_t)t * NBUCKET + q];
    sh[t] = v;
    __syncthreads();
    for (int off = 1; off < 256; off <<= 1) {
        int x = (t >= off) ? sh[t - off] : 0;
        __syncthreads();
        sh[t] += x;
        __syncthreads();
    }
    blk_base[(size_t)t * NBUCKET + q] = sh[t] - v;
    if (t == 255) bucket_total[q] = sh[255];
}

// block-local reduction: sum of total[0..b) using 256 threads + LDS
__device__ __forceinline__ int partial_base(const int* __restrict__ total, int b,
                                            int* sh /*256*/) {
    int t = threadIdx.x;
    int s = 0;
    for (int i = t; i < b; i += 256) s += total[i];
    sh[t] = s;
    __syncthreads();
    for (int off = 128; off >= 1; off >>= 1) {
        if (t < off) sh[t] += sh[t + off];
        __syncthreads();
    }
    int r = sh[0];
    __syncthreads();
    return r;
}

// ---- pass 3: inline full prefix + scatter (dst,src) into part[] -------------
__global__ __launch_bounds__(256) void scatter_pass(const int* __restrict__ src,
                                                    const int* __restrict__ dst, int E,
                                                    int chunk, int shift,
                                                    const int* __restrict__ bucket_total,
                                                    const int* __restrict__ blk_base,
                                                    long long* __restrict__ part) {
    __shared__ int cur[NBUCKET];
    __shared__ int sh[256];
    int b = blockIdx.x, t = threadIdx.x;
    {
        int idx0 = t * 4;
        int v[4];
#pragma unroll
        for (int k = 0; k < 4; ++k) v[k] = bucket_total[idx0 + k];
        int s = v[0] + v[1] + v[2] + v[3];
        sh[t] = s;
        __syncthreads();
        for (int off = 1; off < 256; off <<= 1) {
            int x = (t >= off) ? sh[t - off] : 0;
            __syncthreads();
            sh[t] += x;
            __syncthreads();
        }
        int run = sh[t] - s;
#pragma unroll
        for (int k = 0; k < 4; ++k) {
            cur[idx0 + k] = run;
            run += v[k];
        }
    }
    __syncthreads();
    for (int i = t; i < NBUCKET; i += 256)
        cur[i] += blk_base[(size_t)b * NBUCKET + i];
    __syncthreads();
    int beg = b * chunk;
    int end = beg + chunk; if (end > E) end = E;
    for (int i = beg + t; i < end; i += 256) {
        int d = dst[i], s = src[i];
        int q = d >> shift;
        int p = atomicAdd(&cur[q], 1);
        part[p] = ((long long)(unsigned)d << 32) | (unsigned)s;
    }
}

// ---- bucket_count: local base + LDS count -> degi, dinv, padded total -------
// Slots per node = deg + 1 (self-loop record), padded to 16-multiples.
__global__ __launch_bounds__(256) void bucket_count(const long long* __restrict__ part,
                                                    const int* __restrict__ bucket_total,
                                                    int N, int shift,
                                                    int* __restrict__ degi,
                                                    float* __restrict__ dinv,
                                                    int* __restrict__ padded_total) {
    __shared__ int cnt[128];
    __shared__ int sh[256];
    int b = blockIdx.x, t = threadIdx.x;
    int beg = partial_base(bucket_total, b, sh);
    int end = beg + bucket_total[b];
    if (t < 128) cnt[t] = 0;
    __syncthreads();
    int node0 = b << shift;
    for (int i = beg + t; i < end; i += 256) {
        int d = (int)((unsigned long long)part[i] >> 32);
        atomicAdd(&cnt[d - node0], 1);
    }
    __syncthreads();
    int padded = 0;
    if (t < 128) {
        int node = node0 + t;
        int c = (node < N) ? cnt[t] : 0;
        if (node < N) {
            degi[node] = c;
            dinv[node] = rsqrtf((float)(c + 1));
            padded = ((c + 16) >> 4) << 4;  // ceil((deg+1)/16)*16
        }
    }
    __syncthreads();
    if (t < 128) sh[t] = padded; else sh[t] = 0;
    __syncthreads();
    for (int off = 64; off >= 1; off >>= 1) {
        if (t < off) sh[t] += sh[t + off];
        __syncthreads();
    }
    if (t == 0) padded_total[b] = sh[0];
}

// ---- bucket_fill: row_ptr + self rec + weighted edges + pads into csr2 ------
__global__ __launch_bounds__(256) void bucket_fill(const long long* __restrict__ part,
                                                   const int* __restrict__ bucket_total,
                                                   const int* __restrict__ padded_total,
                                                   const int* __restrict__ degi,
                                                   const float* __restrict__ dinv,
                                                   int N, int shift,
                                                   int* __restrict__ row_ptr,
                                                   long long* __restrict__ csr2) {
    __shared__ int sh[256];
    __shared__ int pexcl[128];
    __shared__ int padarr[128];
    __shared__ int cur[128];
    __shared__ float dvl[128];
    int b = blockIdx.x, t = threadIdx.x;
    int node0 = b << shift;
    int ebeg = partial_base(bucket_total, b, sh);
    int eend = ebeg + bucket_total[b];
    int pbase = partial_base(padded_total, b, sh);

    int padded = 0;
    if (t < 128) {
        int node = node0 + t;
        int deg = (node < N) ? degi[node] : 0;
        dvl[t] = (node < N) ? dinv[node] : 0.0f;
        if (node < N) padded = ((deg + 16) >> 4) << 4;
        padarr[t] = padded;
    }
    __syncthreads();
    if (t < 128) sh[t] = padded;
    __syncthreads();
    for (int off = 1; off < 128; off <<= 1) {
        int x = 0;
        if (t < 128 && t >= off) x = sh[t - off];
        __syncthreads();
        if (t < 128) sh[t] += x;
        __syncthreads();
    }
    if (t < 128) {
        int excl = sh[t] - padarr[t];
        pexcl[t] = excl;
        int node = node0 + t;
        if (node < N) {
            row_ptr[node] = pbase + excl;
            // self-loop record first: (src=node, w=dinv^2)
            float ws = dvl[t] * dvl[t];
            csr2[pbase + excl] = (long long)(unsigned)node |
                                 ((long long)(unsigned)__float_as_uint(ws) << 32);
            cur[t] = pbase + excl + 1;
        } else {
            cur[t] = pbase + excl;
        }
    }
    __syncthreads();
    if (t == 0) {
        int boundary = node0 + 128;
        if (boundary > N) boundary = N;
        row_ptr[boundary] = pbase + sh[127];  // benign overlap with next bucket
    }
    for (int i = ebeg + t; i < eend; i += 256) {
        long long pr = part[i];
        int d = (int)((unsigned long long)pr >> 32);
        int s = (int)(unsigned)(pr & 0xffffffffLL);
        int dl = d - node0;
        int p = atomicAdd(&cur[dl], 1);
        float w = dinv[s] * dvl[dl];
        csr2[p] = (long long)(unsigned)s |
                  ((long long)(unsigned)__float_as_uint(w) << 32);
    }
    __syncthreads();
    if (t < 128) {
        int node = node0 + t;
        if (node < N) {
            int endp = pbase + pexcl[t] + padarr[t];
            long long rec = (long long)(unsigned)node;  // hi=0 -> w=0.0f
            for (int p = cur[t]; p < endp; ++p) csr2[p] = rec;
        }
    }
}

// ---- MFMA GEMM: C[M,128](fp16) = A[M,128] @ Bt^T ---------------------------
template <int AF32>
__global__ __launch_bounds__(256) void gemm_mfma(const void* __restrict__ Av, int M,
                                                 const __half* __restrict__ Bt,
                                                 __half* __restrict__ C) {
    __shared__ __half Bs[128][136];
    int tid = threadIdx.x;
#pragma unroll
    for (int i = 0; i < 8; ++i) {
        int idx = tid + i * 256;
        int r = idx >> 4;
        int c8 = (idx & 15) << 3;
        *(float4*)&Bs[r][c8] = *(const float4*)(Bt + r * 128 + c8);
    }
    __syncthreads();
    int wave = tid >> 6, lane = tid & 63;
    int lr = lane & 15, lk = lane >> 4;
    int row0 = blockIdx.x * 128 + wave * 32;

    f32x4_t acc[2][8];
#pragma unroll
    for (int rt = 0; rt < 2; ++rt)
#pragma unroll
        for (int ct = 0; ct < 8; ++ct) acc[rt][ct] = (f32x4_t)0.0f;

    half8_t afr[2][4];
#pragma unroll
    for (int rt = 0; rt < 2; ++rt) {
        int row = row0 + rt * 16 + lr;
        if (row >= M) row = M - 1;
        if (AF32) {
            const float* A = (const float*)Av + (size_t)row * 128;
#pragma unroll
            for (int ks = 0; ks < 4; ++ks) {
                float4 v0 = *(const float4*)(A + ks * 32 + lk * 8);
                float4 v1 = *(const float4*)(A + ks * 32 + lk * 8 + 4);
                half8_t f;
                f[0] = (_Float16)v0.x; f[1] = (_Float16)v0.y;
                f[2] = (_Float16)v0.z; f[3] = (_Float16)v0.w;
                f[4] = (_Float16)v1.x; f[5] = (_Float16)v1.y;
                f[6] = (_Float16)v1.z; f[7] = (_Float16)v1.w;
                afr[rt][ks] = f;
            }
        } else {
            const __half* A = (const __half*)Av + (size_t)row * 128;
#pragma unroll
            for (int ks = 0; ks < 4; ++ks)
                afr[rt][ks] = *(const half8_t*)(A + ks * 32 + lk * 8);
        }
    }
#pragma unroll
    for (int ks = 0; ks < 4; ++ks)
#pragma unroll
        for (int ct = 0; ct < 8; ++ct) {
            half8_t b = *(const half8_t*)&Bs[ct * 16 + lr][ks * 32 + lk * 8];
            acc[0][ct] = __builtin_amdgcn_mfma_f32_16x16x32_f16(afr[0][ks], b, acc[0][ct], 0, 0, 0);
            acc[1][ct] = __builtin_amdgcn_mfma_f32_16x16x32_f16(afr[1][ks], b, acc[1][ct], 0, 0, 0);
        }
    // C layout (16x16x32_f16): col = lane&15, row = (lane>>4)*4 + reg
#pragma unroll
    for (int rt = 0; rt < 2; ++rt)
#pragma unroll
        for (int r = 0; r < 4; ++r) {
            int row = row0 + rt * 16 + lk * 4 + r;
            if (row < M) {
#pragma unroll
                for (int ct = 0; ct < 8; ++ct)
                    C[(size_t)row * 128 + ct * 16 + lr] = __float2half_rn(acc[rt][ct][r]);
            }
        }
}

// ---- gather: one node per wave, mask-free padded rows, no dinv --------------
// 4 slot-groups x 16 ch-lanes; 4-unroll = 16 slots/iter, 16 rows in flight.
// Self-loop + pads are ordinary csr2 records. Reduce: xor 16, 32.
// MODE 0: out = relu(acc + bias) -> fp16 [n][128]
// MODE 1: out = acc + bias       -> f32 mu [n][64] || logstd [n][64] (nt)
template <int MODE>
__global__ __launch_bounds__(256) void gather_one(const __half* __restrict__ h,
                                                  const int* __restrict__ row_ptr,
                                                  const long long* __restrict__ csr2,
                                                  const float* __restrict__ bias,
                                                  void* __restrict__ outv, int n) {
    int wid = (blockIdx.x * 256 + threadIdx.x) >> 6;
    int lane = threadIdx.x & 63;
    if (wid >= n) return;
    int grp = lane >> 4;   // edge slot within each 16-slot quad
    int cs  = lane & 15;   // channel slice: 8 halves at cs*8
    int beg = row_ptr[wid];
    int end = row_ptr[wid + 1];   // length is a 16-multiple, >= 16

    float acc[8] = {};
#pragma unroll 1
    for (int j = beg; j < end; j += 16) {
        long long e[4];
#pragma unroll
        for (int u = 0; u < 4; ++u) e[u] = csr2[j + u * 4 + grp];
        float4 raw[4];
        float wgt[4];
#pragma unroll
        for (int u = 0; u < 4; ++u) {
            int s = (int)(unsigned)(e[u] & 0xffffffffLL);
            wgt[u] = __uint_as_float((unsigned)((unsigned long long)e[u] >> 32));
            raw[u] = *(const float4*)(h + (size_t)s * 128 + cs * 8);
        }
#pragma unroll
        for (int u = 0; u < 4; ++u) {
            const __half2* hp = (const __half2*)&raw[u];
#pragma unroll
            for (int q = 0; q < 4; ++q) {
                float2 f = __half22float2(hp[q]);
                acc[2 * q]     = fmaf(wgt[u], f.x, acc[2 * q]);
                acc[2 * q + 1] = fmaf(wgt[u], f.y, acc[2 * q + 1]);
            }
        }
    }

    // reduce the 4 slot-groups (lanes xor 16, 32)
#pragma unroll
    for (int q = 0; q < 8; ++q) {
        acc[q] += __shfl_xor(acc[q], 16, 64);
        acc[q] += __shfl_xor(acc[q], 32, 64);
    }

    {
        const float4* bp = (const float4*)(bias + cs * 8);
        float4 b0 = bp[0], b1 = bp[1];
        if (MODE == 0) {
            acc[0] = fmaxf(acc[0] + b0.x, 0.0f);
            acc[1] = fmaxf(acc[1] + b0.y, 0.0f);
            acc[2] = fmaxf(acc[2] + b0.z, 0.0f);
            acc[3] = fmaxf(acc[3] + b0.w, 0.0f);
            acc[4] = fmaxf(acc[4] + b1.x, 0.0f);
            acc[5] = fmaxf(acc[5] + b1.y, 0.0f);
            acc[6] = fmaxf(acc[6] + b1.z, 0.0f);
            acc[7] = fmaxf(acc[7] + b1.w, 0.0f);
        } else {
            acc[0] += b0.x; acc[1] += b0.y; acc[2] += b0.z; acc[3] += b0.w;
            acc[4] += b1.x; acc[5] += b1.y; acc[6] += b1.z; acc[7] += b1.w;
        }
    }

    if (lane < 16) {
        if (MODE == 0) {
            union { __half2 h2[4]; float4 f4; } u;
            u.h2[0] = __floats2half2_rn(acc[0], acc[1]);
            u.h2[1] = __floats2half2_rn(acc[2], acc[3]);
            u.h2[2] = __floats2half2_rn(acc[4], acc[5]);
            u.h2[3] = __floats2half2_rn(acc[6], acc[7]);
            *(float4*)((__half*)outv + (size_t)wid * 128 + cs * 8) = u.f4;
        } else {
            float* mu = (float*)outv;
            float* ls = mu + (size_t)n * 64;
            float* op = (cs < 8) ? (mu + (size_t)wid * 64 + cs * 8)
                                 : (ls + (size_t)wid * 64 + (cs - 8) * 8);
            // d_out is never re-read: nontemporal keeps L2 for the p rows.
            // (clang ext-vector type: __builtin_nontemporal_store rejects
            //  HIP_vector_type float4*)
            f32x4_t v0 = {acc[0], acc[1], acc[2], acc[3]};
            f32x4_t v1 = {acc[4], acc[5], acc[6], acc[7]};
            __builtin_nontemporal_store(v0, (f32x4_t*)op);
            __builtin_nontemporal_store(v1, (f32x4_t*)op + 1);
        }
    }
}

extern "C" void kernel_launch(void* const* d_in, const int* in_sizes, int n_in,
                              void* d_out, int out_size, void* d_ws, size_t ws_size,
                              hipStream_t stream) {
    const float* x   = (const float*)d_in[0];
    const int*  eidx = (const int*)d_in[1];
    const float* W1  = (const float*)d_in[2];
    const float* b1  = (const float*)d_in[3];
    const float* Wmu = (const float*)d_in[4];
    const float* bmu = (const float*)d_in[5];
    const float* Wls = (const float*)d_in[6];
    const float* bls = (const float*)d_in[7];
    float* out = (float*)d_out;

    const int N = in_sizes[0] / 128;  // 100000
    const int E = in_sizes[1] / 2;    // 1600000
    const int* src = eidx;
    const int* dst = eidx + E;

    int shift = 0;
    while (((N - 1) >> shift) >= NBUCKET) ++shift;  // N=100000 -> 7 (bw=128)
    int chunk = (E + NPB - 1) / NPB;

    char* w = (char*)d_ws;
    size_t off = 0;
    auto alloc = [&](size_t bytes) {
        void* p = w + off;
        off += (bytes + 255) & ~(size_t)255;
        return p;
    };
    // persistent region
    int*       row_ptr      = (int*)alloc((size_t)(N + 1) * 4);
    float*     dinv         = (float*)alloc((size_t)N * 4);
    int*       bucket_total = (int*)alloc(NBUCKET * 4);
    int*       padded_total = (int*)alloc(NBUCKET * 4);
    __half*    Wt1          = (__half*)alloc(16384 * 2);
    __half*    Wt2          = (__half*)alloc(16384 * 2);
    float*     bias2        = (float*)alloc(128 * 4);
    size_t csr_cap = (size_t)E + 17u * (size_t)N + 64;  // self + per-node pad
    long long* csr2         = (long long*)alloc(csr_cap * 8);
    __half*    h1           = (__half*)alloc((size_t)N * 128 * 2);
    // region D: partition buffers; then h (fp16), then p (fp16) reuse it
    size_t Dstart = off;
    int*       degi     = (int*)alloc((size_t)N * 4);
    int*       blk_hist = (int*)alloc((size_t)NPB * NBUCKET * 4);
    int*       blk_base = (int*)alloc((size_t)NPB * NBUCKET * 4);
    long long* part     = (long long*)alloc((size_t)E * 8);
    size_t Dearly_end = off;
    __half* h = (__half*)(w + Dstart);
    __half* p = (__half*)(w + Dstart);
    size_t Dend = Dstart + (size_t)N * 128 * 2;
    off = (Dearly_end > Dend) ? Dearly_end : Dend;
    if (off > ws_size) return;  // workspace too small: fail cleanly

    // ---- partition + fused CSR build (5 dispatches) ----
    prep_hist<<<NPB + 64, 256, 0, stream>>>(dst, E, chunk, shift, blk_hist,
                                            W1, Wmu, bmu, Wls, bls, Wt1, Wt2, bias2);
    col_scan<<<NBUCKET, 256, 0, stream>>>(blk_hist, blk_base, bucket_total);
    scatter_pass<<<NPB, 256, 0, stream>>>(src, dst, E, chunk, shift,
                                          bucket_total, blk_base, part);
    bucket_count<<<NBUCKET, 256, 0, stream>>>(part, bucket_total, N, shift,
                                              degi, dinv, padded_total);
    bucket_fill<<<NBUCKET, 256, 0, stream>>>(part, bucket_total, padded_total,
                                             degi, dinv, N, shift, row_ptr, csr2);

    // ---- compute (4 dispatches) ----
    int gemm_blocks = (N + 127) / 128;
    int gblocks = ((size_t)N * 64 + 255) / 256;
    // h = x @ W1  (fp16)
    gemm_mfma<1><<<gemm_blocks, 256, 0, stream>>>(x, N, Wt1, h);
    // h1 = relu(A @ h + b1)  (fp16)
    gather_one<0><<<gblocks, 256, 0, stream>>>(h, row_ptr, csr2, b1, h1, N);
    // p = h1 @ [Wmu|Wls]  (fp16)
    gemm_mfma<0><<<gemm_blocks, 256, 0, stream>>>(h1, N, Wt2, p);
    // mu|logstd = A @ p + bias2  -> d_out (f32 halves)
    gather_one<1><<<gblocks, 256, 0, stream>>>(p, row_ptr, csr2, bias2, out, N);
}